// Round 4
// baseline (76.174 us; speedup 1.0000x reference)
//
#include <hip/hip_runtime.h>
#include <hip/hip_bf16.h>
#include <stdint.h>

typedef float  f32x4  __attribute__((ext_vector_type(4)));
typedef float  f32x2  __attribute__((ext_vector_type(2)));
typedef __bf16 bf16x8 __attribute__((ext_vector_type(8)));

#define LROW 40   // bf16 elems per LDS row (32 data + 8 pad) => 80B stride

// ---------------- weight prep: f32 -> bf16, [tensor][o][k] ----------------
__global__ __launch_bounds__(256) void wprep_kernel(
    const float* __restrict__ Wq, const float* __restrict__ Wk,
    const float* __restrict__ Wv, __bf16* __restrict__ Wbf)
{
  const int b = blockIdx.x;            // 0..95
  const int t = b >> 5;                // tensor
  const float* src = (t == 0) ? Wq : (t == 1) ? Wk : Wv;
  const int off = (b & 31) * 2048 + threadIdx.x * 8;
  f32x4 v0 = *(const f32x4*)(src + off);
  f32x4 v1 = *(const f32x4*)(src + off + 4);
  bf16x8 r;
#pragma unroll
  for (int q = 0; q < 4; ++q) { r[q] = (__bf16)v0[q]; r[q + 4] = (__bf16)v1[q]; }
  *(bf16x8*)(Wbf + t * 65536 + off) = r;
}

// ---------------- merged projection GEMM (2 panels / block) ----------------
// Block = 128 pixels x {two 128-row weight panels}. Types per pixel tile:
//   0: (Q,o=0)+(Q,o=128) from blue; 1: (K,0)+(V,0) from white; 2: (K,128)+(V,128).
// A-fragments load directly from bf16 weights in L2 (no LDS for A).
// B double-buffered in LDS; ONE raw s_barrier per K-step (no vmcnt drain),
// next-tile B global loads stay in flight across the barrier.

__global__ __launch_bounds__(256) void proj_gemm2_kernel(
    const float* __restrict__ blue, const float* __restrict__ white,
    const __bf16* __restrict__ Wbf,
    const float* __restrict__ bq, const float* __restrict__ bk,
    const float* __restrict__ bv,
    __bf16* __restrict__ Qt, __bf16* __restrict__ Kt, __bf16* __restrict__ Vt)
{
  __shared__ __bf16 Bs[2][128 * LROW];

  const int bidhw = blockIdx.x;                   // 768 = 8 XCDs * 96
  const int lid   = (bidhw & 7) * 96 + (bidhw >> 3);
  const int nb    = lid / 3;
  const int ty    = lid - nb * 3;

  const float* X = (ty == 0) ? blue : white;
  const __bf16 *W0, *W1; const float *bias0, *bias1;
  __bf16 *Out0, *Out1; int oo0, oo1;
  if (ty == 0)      { W0 = Wbf;                     W1 = Wbf + 128 * 256;
                      bias0 = bq; bias1 = bq; Out0 = Qt; Out1 = Qt; oo0 = 0;   oo1 = 128; }
  else if (ty == 1) { W0 = Wbf + 65536;             W1 = Wbf + 2 * 65536;
                      bias0 = bk; bias1 = bv; Out0 = Kt; Out1 = Vt; oo0 = 0;   oo1 = 0;   }
  else              { W0 = Wbf + 65536 + 128 * 256; W1 = Wbf + 2 * 65536 + 128 * 256;
                      bias0 = bk; bias1 = bv; Out0 = Kt; Out1 = Vt; oo0 = 128; oo1 = 128; }

  const int tid  = threadIdx.x;
  const int lane = tid & 63;
  const int wave = tid >> 6;
  const int wo   = wave >> 1;    // o half within panel (64)
  const int wn   = wave & 1;     // n half (64)

  const int n0    = nb * 128;
  const int batch = n0 >> 12;
  const int p0    = n0 & 4095;
  const int tk0   = p0 >> 4;
  const int trow  = tk0 >> 4;
  const int tcol0 = tk0 & 15;
  const float* Xb = X + (size_t)batch * (256 * 4096);

  // B staging role: thread = (pixel-pair n2, k-octet ko)
  const int n2   = tid & 63;
  const int ko   = tid >> 6;            // wave-uniform
  const int nloc = 2 * n2;
  const int tl   = nloc >> 4;
  const int d    = nloc & 15;
  const int hw   = (trow * 4 + (d >> 2)) * 64 + (tcol0 + tl) * 4 + (d & 3);
  const float* srcB0 = Xb + (size_t)(ko * 8) * 4096 + hw;

  f32x2 pre[8];
#define LOADB(kk) { const float* s_ = srcB0 + (size_t)(kk) * 32 * 4096;            \
    pre[0] = *(const f32x2*)(s_);         pre[1] = *(const f32x2*)(s_ + 4096);     \
    pre[2] = *(const f32x2*)(s_ + 8192);  pre[3] = *(const f32x2*)(s_ + 12288);    \
    pre[4] = *(const f32x2*)(s_ + 16384); pre[5] = *(const f32x2*)(s_ + 20480);    \
    pre[6] = *(const f32x2*)(s_ + 24576); pre[7] = *(const f32x2*)(s_ + 28672); }

  const int lrow = lane & 15;
  const int lk   = (lane >> 4) * 8;
  const int aoff = (wo * 64 + lrow) * 256 + lk;   // + i*4096 + kk*32

  f32x4 acc[2][4][4];
#pragma unroll
  for (int p = 0; p < 2; ++p)
#pragma unroll
    for (int i = 0; i < 4; ++i)
#pragma unroll
      for (int j = 0; j < 4; ++j) acc[p][i][j] = (f32x4)0.0f;

  LOADB(0);

  for (int kk = 0; kk < 8; ++kk) {
    // convert + write tile kk into Bs[kk&1] (waits vmcnt for pre only)
    __bf16* bsw = &Bs[kk & 1][0];
    bf16x8 r0, r1;
#pragma unroll
    for (int t = 0; t < 8; ++t) { r0[t] = (__bf16)pre[t][0]; r1[t] = (__bf16)pre[t][1]; }
    *(bf16x8*)(bsw + (nloc + 0) * LROW + ko * 8) = r0;
    *(bf16x8*)(bsw + (nloc + 1) * LROW + ko * 8) = r1;

    // issue A-fragment loads (L2 bf16) BEFORE next-tile B loads, so the
    // vmcnt wait for af does not drain the B prefetch
    bf16x8 af0[4], af1[4];
#pragma unroll
    for (int i = 0; i < 4; ++i) af0[i] = *(const bf16x8*)(W0 + aoff + i * 4096 + kk * 32);
#pragma unroll
    for (int i = 0; i < 4; ++i) af1[i] = *(const bf16x8*)(W1 + aoff + i * 4096 + kk * 32);

    if (kk < 7) LOADB(kk + 1);   // stays in flight across the barrier

    asm volatile("s_waitcnt lgkmcnt(0)" ::: "memory");
    __builtin_amdgcn_s_barrier();
    asm volatile("" ::: "memory");

    const __bf16* bsr = &Bs[kk & 1][0];
    bf16x8 bfrag[4];
#pragma unroll
    for (int j = 0; j < 4; ++j)
      bfrag[j] = *(const bf16x8*)(bsr + (wn * 64 + j * 16 + lrow) * LROW + lk);
#pragma unroll
    for (int i = 0; i < 4; ++i)
#pragma unroll
      for (int j = 0; j < 4; ++j) {
        acc[0][i][j] = __builtin_amdgcn_mfma_f32_16x16x32_bf16(af0[i], bfrag[j], acc[0][i][j], 0, 0, 0);
        acc[1][i][j] = __builtin_amdgcn_mfma_f32_16x16x32_bf16(af1[i], bfrag[j], acc[1][i][j], 0, 0, 0);
      }
  }
#undef LOADB

  // ---- epilogue: bias add, write bf16 layout [b][ti][c][tj][16]
#pragma unroll
  for (int p = 0; p < 2; ++p) {
    const __bf16* Wdummy = p ? W1 : W0; (void)Wdummy;
    __bf16* Out = p ? Out1 : Out0;
    const float* bias = p ? bias1 : bias0;
    const int oo = p ? oo1 : oo0;
#pragma unroll
    for (int i = 0; i < 4; ++i) {
      const int orow = wo * 64 + i * 16 + (lane >> 4) * 4;
#pragma unroll
      for (int j = 0; j < 4; ++j) {
        const int n  = n0 + wn * 64 + j * 16 + (lane & 15);
        const int bb = n >> 12;
        const int pp = n & 4095;
        const int tt = pp >> 4;
        const int tii = tt >> 4;
        const int tjj = tt & 15;
        const int dd  = pp & 15;
        const size_t base = ((size_t)(bb * 16 + tii) * 256) * 256 + tjj * 16 + dd;
#pragma unroll
        for (int r = 0; r < 4; ++r) {
          const int o = oo + orow + r;
          const float v = acc[p][i][j][r] + bias[o];
          Out[base + (size_t)o * 256] = (__bf16)v;
        }
      }
    }
  }
}

// ---------------- fallback: round-2 self-contained projection ----------------
__global__ __launch_bounds__(256) void proj_gemm_kernel(
    const float* __restrict__ blue, const float* __restrict__ white,
    const float* __restrict__ Wq, const float* __restrict__ bq,
    const float* __restrict__ Wk, const float* __restrict__ bk,
    const float* __restrict__ Wv, const float* __restrict__ bv,
    __bf16* __restrict__ Qt, __bf16* __restrict__ Kt, __bf16* __restrict__ Vt)
{
  __shared__ __bf16 As[128 * LROW];
  __shared__ __bf16 Bs[128 * LROW];

  const int bidhw = blockIdx.x;
  const int lid   = (bidhw & 7) * 192 + (bidhw >> 3);
  const int nb    = lid / 6;
  const int bt    = lid % 6;
  const int tensor = (bt < 4) ? 1 + (bt & 1) : 0;
  const int ob     = (bt < 4) ? (bt >> 1) : (bt & 1);

  const float* X    = (tensor == 0) ? blue : white;
  const float* W    = (tensor == 0) ? Wq : (tensor == 1) ? Wk : Wv;
  const float* bias = (tensor == 0) ? bq : (tensor == 1) ? bk : bv;
  __bf16*      Out  = (tensor == 0) ? Qt : (tensor == 1) ? Kt : Vt;

  const int tid  = threadIdx.x;
  const int lane = tid & 63;
  const int wave = tid >> 6;
  const int wo   = wave >> 1;
  const int wn   = wave & 1;

  const int o0 = ob * 128;
  const int n0 = nb * 128;
  const int batch = n0 >> 12;
  const int p0    = n0 & 4095;
  const int tk0   = p0 >> 4;
  const int trow  = tk0 >> 4;
  const int tcol0 = tk0 & 15;
  const float* Xb = X + (size_t)batch * (256 * 4096);

  f32x4 acc[4][4];
#pragma unroll
  for (int i = 0; i < 4; ++i)
#pragma unroll
    for (int j = 0; j < 4; ++j) acc[i][j] = (f32x4)0.0f;

  const int arow  = tid >> 1;
  const int ahalf = tid & 1;
  const int n2   = tid & 63;
  const int ko   = tid >> 6;
  const int nloc = 2 * n2;
  const int tl   = nloc >> 4;
  const int d    = nloc & 15;
  const int hw   = (trow * 4 + (d >> 2)) * 64 + (tcol0 + tl) * 4 + (d & 3);

  const int lrow = lane & 15;
  const int lk   = (lane >> 4) * 8;

  for (int kk = 0; kk < 8; ++kk) {
    const int k0 = kk * 32;
    {
      const float* src = W + (size_t)(o0 + arow) * 256 + k0 + ahalf * 16;
      f32x4 t0 = *(const f32x4*)(src + 0);
      f32x4 t1 = *(const f32x4*)(src + 4);
      f32x4 t2 = *(const f32x4*)(src + 8);
      f32x4 t3 = *(const f32x4*)(src + 12);
      bf16x8 c0, c1;
#pragma unroll
      for (int q = 0; q < 4; ++q) { c0[q] = (__bf16)t0[q]; c0[q + 4] = (__bf16)t1[q]; }
#pragma unroll
      for (int q = 0; q < 4; ++q) { c1[q] = (__bf16)t2[q]; c1[q + 4] = (__bf16)t3[q]; }
      __bf16* dst = As + arow * LROW + ahalf * 16;
      *(bf16x8*)(dst + 0) = c0;
      *(bf16x8*)(dst + 8) = c1;
    }
    {
      const float* src = Xb + (size_t)(k0 + ko * 8) * 4096 + hw;
      f32x2 v0 = *(const f32x2*)(src + 0 * 4096);
      f32x2 v1 = *(const f32x2*)(src + 1 * 4096);
      f32x2 v2 = *(const f32x2*)(src + 2 * 4096);
      f32x2 v3 = *(const f32x2*)(src + 3 * 4096);
      f32x2 v4 = *(const f32x2*)(src + 4 * 4096);
      f32x2 v5 = *(const f32x2*)(src + 5 * 4096);
      f32x2 v6 = *(const f32x2*)(src + 6 * 4096);
      f32x2 v7 = *(const f32x2*)(src + 7 * 4096);
      bf16x8 r0, r1;
      r0[0] = (__bf16)v0[0]; r0[1] = (__bf16)v1[0]; r0[2] = (__bf16)v2[0]; r0[3] = (__bf16)v3[0];
      r0[4] = (__bf16)v4[0]; r0[5] = (__bf16)v5[0]; r0[6] = (__bf16)v6[0]; r0[7] = (__bf16)v7[0];
      r1[0] = (__bf16)v0[1]; r1[1] = (__bf16)v1[1]; r1[2] = (__bf16)v2[1]; r1[3] = (__bf16)v3[1];
      r1[4] = (__bf16)v4[1]; r1[5] = (__bf16)v5[1]; r1[6] = (__bf16)v6[1]; r1[7] = (__bf16)v7[1];
      *(bf16x8*)(Bs + (nloc + 0) * LROW + ko * 8) = r0;
      *(bf16x8*)(Bs + (nloc + 1) * LROW + ko * 8) = r1;
    }
    __syncthreads();

    bf16x8 a[4], b[4];
#pragma unroll
    for (int i = 0; i < 4; ++i)
      a[i] = *(const bf16x8*)(As + (wo * 64 + i * 16 + lrow) * LROW + lk);
#pragma unroll
    for (int j = 0; j < 4; ++j)
      b[j] = *(const bf16x8*)(Bs + (wn * 64 + j * 16 + lrow) * LROW + lk);
#pragma unroll
    for (int i = 0; i < 4; ++i)
#pragma unroll
      for (int j = 0; j < 4; ++j)
        acc[i][j] = __builtin_amdgcn_mfma_f32_16x16x32_bf16(a[i], b[j], acc[i][j], 0, 0, 0);
    __syncthreads();
  }

#pragma unroll
  for (int i = 0; i < 4; ++i) {
    const int obase = o0 + wo * 64 + i * 16 + (lane >> 4) * 4;
#pragma unroll
    for (int j = 0; j < 4; ++j) {
      const int n  = n0 + wn * 64 + j * 16 + (lane & 15);
      const int bb = n >> 12;
      const int p  = n & 4095;
      const int tt = p >> 4;
      const int tii = tt >> 4;
      const int tjj = tt & 15;
      const int dd  = p & 15;
      const size_t base = ((size_t)(bb * 16 + tii) * 256) * 256 + tjj * 16 + dd;
#pragma unroll
      for (int r = 0; r < 4; ++r) {
        const int o = obase + r;
        const float v = acc[i][j][r] + bias[o];
        Out[base + (size_t)o * 256] = (__bf16)v;
      }
    }
  }
}

// ---------------- fused neighborhood attention + residual ----------------
__device__ __forceinline__ void unpack8(const uint4 v, float* f) {
  const uint32_t u0 = v.x, u1 = v.y, u2 = v.z, u3 = v.w;
  f[0] = __uint_as_float(u0 << 16); f[1] = __uint_as_float(u0 & 0xffff0000u);
  f[2] = __uint_as_float(u1 << 16); f[3] = __uint_as_float(u1 & 0xffff0000u);
  f[4] = __uint_as_float(u2 << 16); f[5] = __uint_as_float(u2 & 0xffff0000u);
  f[6] = __uint_as_float(u3 << 16); f[7] = __uint_as_float(u3 & 0xffff0000u);
}

__global__ __launch_bounds__(256) void attn_kernel(
    const __bf16* __restrict__ Qt, const __bf16* __restrict__ Kt,
    const __bf16* __restrict__ Vt, const float* __restrict__ blue,
    float* __restrict__ out)
{
  const int j   = blockIdx.x;
  const int bid = (j & 7) * 256 + (j >> 3);
  const int cg  = bid & 15;
  const int ti  = (bid >> 4) & 15;
  const int b   = bid >> 8;

  const int tid = threadIdx.x;
  const int tj  = tid & 15;
  const int cl  = tid >> 4;
  const int c   = cg * 16 + cl;

  float q[16];
  {
    const __bf16* p = Qt + ((((size_t)b * 16 + ti) * 256 + c) * 16 + tj) * 16;
    unpack8(*(const uint4*)p, q);
    unpack8(*(const uint4*)(p + 8), q + 8);
  }

  float s[9];
#pragma unroll
  for (int n = 0; n < 9; ++n) {
    const int yi = ti + n / 3 - 1;
    const int yj = tj + n % 3 - 1;
    float dot = 0.0f;
    if (yi >= 0 && yi < 16 && yj >= 0 && yj < 16) {
      const __bf16* p = Kt + ((((size_t)b * 16 + yi) * 256 + c) * 16 + yj) * 16;
      float kf[16];
      unpack8(*(const uint4*)p, kf);
      unpack8(*(const uint4*)(p + 8), kf + 8);
#pragma unroll
      for (int dd = 0; dd < 16; ++dd) dot = fmaf(q[dd], kf[dd], dot);
    }
    s[n] = dot * 0.25f;
  }

  float m = s[0];
#pragma unroll
  for (int n = 1; n < 9; ++n) m = fmaxf(m, s[n]);
  float w[9], denom = 0.0f;
#pragma unroll
  for (int n = 0; n < 9; ++n) { w[n] = __expf(s[n] - m); denom += w[n]; }
  const float inv = 1.0f / denom;

  float o16[16];
#pragma unroll
  for (int dd = 0; dd < 16; ++dd) o16[dd] = 0.0f;
#pragma unroll
  for (int n = 0; n < 9; ++n) {
    const int yi = ti + n / 3 - 1;
    const int yj = tj + n % 3 - 1;
    if (yi >= 0 && yi < 16 && yj >= 0 && yj < 16) {
      const __bf16* p = Vt + ((((size_t)b * 16 + yi) * 256 + c) * 16 + yj) * 16;
      float vf[16];
      unpack8(*(const uint4*)p, vf);
      unpack8(*(const uint4*)(p + 8), vf + 8);
#pragma unroll
      for (int dd = 0; dd < 16; ++dd) o16[dd] = fmaf(w[n], vf[dd], o16[dd]);
    }
  }

  const size_t pbase = ((size_t)b * 256 + c) * 4096 + (size_t)(ti * 4) * 64 + tj * 4;
#pragma unroll
  for (int r = 0; r < 4; ++r) {
    f32x4 bl = *(const f32x4*)(blue + pbase + r * 64);
    f32x4 ov;
#pragma unroll
    for (int j2 = 0; j2 < 4; ++j2) ov[j2] = bl[j2] + o16[r * 4 + j2] * inv;
    *(f32x4*)(out + pbase + r * 64) = ov;
  }
}

// ---------------- launcher ----------------
extern "C" void kernel_launch(void* const* d_in, const int* in_sizes, int n_in,
                              void* d_out, int out_size, void* d_ws, size_t ws_size,
                              hipStream_t stream) {
  const float* blue  = (const float*)d_in[0];
  const float* white = (const float*)d_in[1];
  const float* Wq = (const float*)d_in[2];
  const float* bq = (const float*)d_in[3];
  const float* Wk = (const float*)d_in[4];
  const float* bk = (const float*)d_in[5];
  const float* Wv = (const float*)d_in[6];
  const float* bv = (const float*)d_in[7];
  float* out = (float*)d_out;

  const size_t tsz = (size_t)8 * 256 * 256 * 16;   // elems per tensor
  __bf16* Qt = (__bf16*)d_ws;
  __bf16* Kt = Qt + tsz;
  __bf16* Vt = Kt + tsz;

  const size_t need = (3 * tsz + 3 * 65536) * sizeof(__bf16);
  if (ws_size >= need) {
    __bf16* Wbf = Vt + tsz;
    wprep_kernel<<<96, 256, 0, stream>>>(Wq, Wk, Wv, Wbf);
    proj_gemm2_kernel<<<768, 256, 0, stream>>>(blue, white, Wbf, bq, bk, bv, Qt, Kt, Vt);
  } else {
    proj_gemm_kernel<<<1536, 256, 0, stream>>>(blue, white, Wq, bq, Wk, bk, Wv, bv, Qt, Kt, Vt);
  }
  attn_kernel<<<2048, 256, 0, stream>>>(Qt, Kt, Vt, blue, out);
}